// Round 3
// baseline (405.913 us; speedup 1.0000x reference)
//
#include <hip/hip_runtime.h>

// GraphSAGE 2-layer. Round 9 resubmit (round 10): MLP-boosted gathers —
// persistent grid-stride waves (2048 blocks = resident capacity), next-node
// rs[] prefetch, 8-wide edge blocks (8 row loads in flight), clamped 8-wide
// tail with 0/1-weight pk_fma (no serial remainder). Scalarized addressing
// kept from round 8. Rest unchanged (register-prefetch gemm1, gemm2_dual,
// bucket CSR build). Prior bench attempt hit GPUAcquisitionTimeout.

#define NSRC 200000
#define NMID 100000
#define NTGT 50000
#define NE1  1600000
#define NE2  800000
#define DIN  128
#define DHID 256
#define DOUT 64

#define XCH (NSRC * 16)

#define CH   4096
#define NBK1 391
#define NBK2 196
#define NCH1 ((NE1 + CH - 1) / CH)
#define NCH2 ((NE2 + CH - 1) / CH)
#define HCH  8192
#define NHC1 ((NE1 + HCH - 1) / HCH)
#define NHC2 ((NE2 + HCH - 1) / HCH)
#define MAXBUF 6144

#define GBLK 2048
#define WSTRIDE (GBLK * 4)

typedef __attribute__((ext_vector_type(8))) short bf16x8;
typedef __attribute__((ext_vector_type(4))) float f32x4;
typedef __attribute__((ext_vector_type(2))) float f32x2;

__device__ __forceinline__ unsigned short f2bf(float f) {
    unsigned int u = __builtin_bit_cast(unsigned int, f);
    u += 0x7FFFu + ((u >> 16) & 1u);
    return (unsigned short)(u >> 16);
}
__device__ __forceinline__ float bf_lo(unsigned int u) {
    return __builtin_bit_cast(float, u << 16);
}
__device__ __forceinline__ float bf_hi(unsigned int u) {
    return __builtin_bit_cast(float, u & 0xFFFF0000u);
}

// ---------------- fused converts ----------------
__global__ __launch_bounds__(256) void convert_all_kernel(
    const float* __restrict__ x,
    const float* __restrict__ Wl1, const float* __restrict__ Wr1,
    const float* __restrict__ Wl2, const float* __restrict__ Wr2,
    unsigned short* __restrict__ xb, unsigned short* __restrict__ WT1,
    unsigned short* __restrict__ WT2)
{
    int gid = blockIdx.x * 256 + threadIdx.x;
    if (gid < XCH) {
        const float4 v0 = *(const float4*)(x + (long long)gid * 8);
        const float4 v1 = *(const float4*)(x + (long long)gid * 8 + 4);
        unsigned short o[8] = {f2bf(v0.x), f2bf(v0.y), f2bf(v0.z), f2bf(v0.w),
                               f2bf(v1.x), f2bf(v1.y), f2bf(v1.z), f2bf(v1.w)};
        *(uint4*)(xb + (long long)gid * 8) = *(const uint4*)o;
        return;
    }
    int g = gid - XCH;
    if (g < 65536) {
        int n = g >> 8, k = g & 255;
        float v = (k < DIN) ? Wl1[(long long)k * DHID + n]
                            : Wr1[(long long)(k - DIN) * DHID + n];
        WT1[g] = f2bf(v);
        return;
    }
    g -= 65536;
    if (g < 32768) {
        int n2 = g >> 8, k = g & 255;
        float v = (n2 < DOUT) ? Wl2[(long long)k * DOUT + n2]
                              : Wr2[(long long)k * DOUT + (n2 - DOUT)];
        WT2[g] = f2bf(v);
    }
}

// ---------------- bucket-first CSR build ----------------

__global__ __launch_bounds__(256) void bucket_hist_kernel(
    const int* __restrict__ ei1, const int* __restrict__ ei2,
    int* __restrict__ bhist1, int* __restrict__ bhist2)
{
    __shared__ unsigned int lh[512];
    const int* ei; int* bh; int nE, nbk, chunk;
    if (blockIdx.x < NHC1) { ei = ei1; bh = bhist1; nE = NE1; nbk = NBK1; chunk = blockIdx.x; }
    else { ei = ei2; bh = bhist2; nE = NE2; nbk = NBK2; chunk = blockIdx.x - NHC1; }
    int t = threadIdx.x;
    lh[t] = 0; lh[t + 256] = 0;
    __syncthreads();
    int base = chunk * HCH;
    int end = nE < base + HCH ? nE : base + HCH;
    for (int e = base + t; e < end; e += 256)
        atomicAdd(&lh[((unsigned)ei[nE + e]) >> 8], 1u);
    __syncthreads();
    if (t < nbk && lh[t]) atomicAdd(&bh[t], (int)lh[t]);
    if (t + 256 < nbk && lh[t + 256]) atomicAdd(&bh[t + 256], (int)lh[t + 256]);
}

__global__ __launch_bounds__(256) void bucket_scan_kernel(
    const int* __restrict__ bhist1, const int* __restrict__ bhist2,
    int* __restrict__ bbase1, int* __restrict__ bbase2,
    int* __restrict__ bcur1, int* __restrict__ bcur2,
    int* __restrict__ rs1, int* __restrict__ rs2)
{
    __shared__ int s[256];
    int t = threadIdx.x;
    int a0 = (2 * t < NBK1) ? bhist1[2 * t] : 0;
    int a1 = (2 * t + 1 < NBK1) ? bhist1[2 * t + 1] : 0;
    s[t] = a0 + a1;
    __syncthreads();
    for (int off = 1; off < 256; off <<= 1) {
        int u = (t >= off) ? s[t - off] : 0;
        __syncthreads();
        s[t] += u;
        __syncthreads();
    }
    int ex = (t > 0) ? s[t - 1] : 0;
    if (2 * t < NBK1)     { bbase1[2 * t] = ex;      bcur1[2 * t] = ex; }
    if (2 * t + 1 < NBK1) { bbase1[2 * t + 1] = ex + a0; bcur1[2 * t + 1] = ex + a0; }
    if (t == 0) { bbase1[NBK1] = NE1; rs1[NMID] = NE1; bbase2[NBK2] = NE2; rs2[NTGT] = NE2; }
    __syncthreads();
    int b0 = (t < NBK2) ? bhist2[t] : 0;
    s[t] = b0;
    __syncthreads();
    for (int off = 1; off < 256; off <<= 1) {
        int u = (t >= off) ? s[t - off] : 0;
        __syncthreads();
        s[t] += u;
        __syncthreads();
    }
    int ex2 = (t > 0) ? s[t - 1] : 0;
    if (t < NBK2) { bbase2[t] = ex2; bcur2[t] = ex2; }
}

__global__ __launch_bounds__(256) void bin_kernel(
    const int* __restrict__ ei1, const int* __restrict__ ei2,
    int* __restrict__ bcur1, int* __restrict__ bcur2,
    uint2* __restrict__ gbuf1, uint2* __restrict__ gbuf2)
{
    __shared__ unsigned int lcnt[512];
    __shared__ unsigned int lofs[512];
    __shared__ unsigned int lpos[512];
    __shared__ unsigned int gbase[512];
    __shared__ unsigned int swarp[256];
    __shared__ uint2 lbuf[CH];

    const int* ei; int* bcur; uint2* gbuf; int nE, nbk, chunk;
    if (blockIdx.x < NCH1) {
        ei = ei1; bcur = bcur1; gbuf = gbuf1; nE = NE1; nbk = NBK1; chunk = blockIdx.x;
    } else {
        ei = ei2; bcur = bcur2; gbuf = gbuf2; nE = NE2; nbk = NBK2; chunk = blockIdx.x - NCH1;
    }
    int base = chunk * CH;
    int nb = nE - base; if (nb > CH) nb = CH;
    int t = threadIdx.x;

    for (int i = t; i < 512; i += 256) { lcnt[i] = 0; lpos[i] = 0; }
    __syncthreads();

    int srcv[16], tgtv[16];
    #pragma unroll
    for (int i = 0; i < 16; ++i) {
        int e = base + i * 256 + t;
        if (e < nE) {
            tgtv[i] = ei[nE + e];
            srcv[i] = ei[e];
            atomicAdd(&lcnt[tgtv[i] >> 8], 1u);
        } else tgtv[i] = -1;
    }
    __syncthreads();

    unsigned a0 = lcnt[2 * t], a1 = lcnt[2 * t + 1];
    swarp[t] = a0 + a1;
    __syncthreads();
    for (int off = 1; off < 256; off <<= 1) {
        unsigned v = (t >= off) ? swarp[t - off] : 0;
        __syncthreads();
        swarp[t] += v;
        __syncthreads();
    }
    unsigned ex = (t > 0) ? swarp[t - 1] : 0;
    lofs[2 * t] = ex;
    lofs[2 * t + 1] = ex + a0;
    if (2 * t < nbk && a0) gbase[2 * t] = atomicAdd(&bcur[2 * t], (int)a0);
    if (2 * t + 1 < nbk && a1) gbase[2 * t + 1] = atomicAdd(&bcur[2 * t + 1], (int)a1);
    __syncthreads();

    #pragma unroll
    for (int i = 0; i < 16; ++i) {
        if (tgtv[i] >= 0) {
            int b = tgtv[i] >> 8;
            unsigned idx = lofs[b] + atomicAdd(&lpos[b], 1u);
            lbuf[idx] = make_uint2((unsigned)srcv[i], (unsigned)tgtv[i]);
        }
    }
    __syncthreads();

    for (int i = t; i < nb; i += 256) {
        uint2 r = lbuf[i];
        int b = (int)(r.y >> 8);
        unsigned gi = gbase[b] + ((unsigned)i - lofs[b]);
        gbuf[gi] = r;
    }
}

__global__ __launch_bounds__(256) void bucket_csr_kernel(
    const uint2* __restrict__ gbuf1, const uint2* __restrict__ gbuf2,
    const int* __restrict__ bbase1, const int* __restrict__ bbase2,
    int* __restrict__ rs1, int* __restrict__ rs2,
    int* __restrict__ csr1, int* __restrict__ csr2)
{
    __shared__ unsigned int lhist[256];
    __shared__ unsigned int lcur[256];
    __shared__ unsigned int sscan[256];
    __shared__ unsigned int lbuf[MAXBUF];
    const uint2* gbuf; const int* bbase; int* rs; int* csr; int bucket, ntot;
    if (blockIdx.x < NBK1) {
        gbuf = gbuf1; bbase = bbase1; rs = rs1; csr = csr1; bucket = blockIdx.x; ntot = NMID;
    } else {
        gbuf = gbuf2; bbase = bbase2; rs = rs2; csr = csr2; bucket = blockIdx.x - NBK1; ntot = NTGT;
    }
    int base = bbase[bucket];
    int size = bbase[bucket + 1] - base;
    int node0 = bucket << 8;
    int nnode = ntot - node0; if (nnode > 256) nnode = 256;
    int t = threadIdx.x;
    lhist[t] = 0;
    __syncthreads();
    for (int i = t; i < size; i += 256)
        atomicAdd(&lhist[gbuf[base + i].y & 255], 1u);
    __syncthreads();
    unsigned v = lhist[t];
    sscan[t] = v;
    __syncthreads();
    for (int off = 1; off < 256; off <<= 1) {
        unsigned u = (t >= off) ? sscan[t - off] : 0;
        __syncthreads();
        sscan[t] += u;
        __syncthreads();
    }
    unsigned ex = (t > 0) ? sscan[t - 1] : 0;
    lcur[t] = ex;
    if (t < nnode) rs[node0 + t] = base + (int)ex;
    __syncthreads();
    for (int i = t; i < size; i += 256) {
        uint2 r = gbuf[base + i];
        unsigned pos = atomicAdd(&lcur[r.y & 255], 1u);
        lbuf[pos] = r.x;
    }
    __syncthreads();
    for (int i = t; i < size; i += 256)
        csr[base + i] = (int)lbuf[i];
}

// ---------------- gathers (scalarized, MLP-boosted, persistent) ----------------
// One wave per node, grid-stride. Node index forced into SGPR so rs/csr reads
// are s_load and row loads use the saddr form. 8 row loads in flight per
// block; next node's rs[] prefetched before processing current; tail handled
// as one clamped 8-wide block with 0/1-weight fma (no serial remainder).

__global__ __launch_bounds__(256) void gather1_kernel(
    const unsigned short* __restrict__ xb, const int* __restrict__ rs,
    const int* __restrict__ csr, unsigned short* __restrict__ aggnb)
{
    const int lane = threadIdx.x & 63;
    const unsigned int* xw = (const unsigned int*)xb;   // 64 uints per row
    int nv = blockIdx.x * 4 + (threadIdx.x >> 6);
    if (nv >= NMID) return;
    int node = __builtin_amdgcn_readfirstlane(nv);
    int s = rs[node];
    int e = rs[node + 1];
    while (true) {
        // prefetch next node's row-range while current node's loads run
        int nvn = nv + WSTRIDE;
        int sn = 0, en = 0;
        if (nvn < NMID) {
            int nn = __builtin_amdgcn_readfirstlane(nvn);
            sn = rs[nn];
            en = rs[nn + 1];
        }
        int d = e - s;
        f32x2 a0 = {0.f,0.f}, a1 = {0.f,0.f}, a2 = {0.f,0.f}, a3 = {0.f,0.f};
        f32x2 a4 = {0.f,0.f}, a5 = {0.f,0.f}, a6 = {0.f,0.f}, a7 = {0.f,0.f};
        int j = 0;
        for (; j + 8 <= d; j += 8) {
            int i0 = csr[s + j + 0], i1 = csr[s + j + 1];
            int i2 = csr[s + j + 2], i3 = csr[s + j + 3];
            int i4 = csr[s + j + 4], i5 = csr[s + j + 5];
            int i6 = csr[s + j + 6], i7 = csr[s + j + 7];
            unsigned u0 = xw[((size_t)(unsigned)i0 << 6) + lane];
            unsigned u1 = xw[((size_t)(unsigned)i1 << 6) + lane];
            unsigned u2 = xw[((size_t)(unsigned)i2 << 6) + lane];
            unsigned u3 = xw[((size_t)(unsigned)i3 << 6) + lane];
            unsigned u4 = xw[((size_t)(unsigned)i4 << 6) + lane];
            unsigned u5 = xw[((size_t)(unsigned)i5 << 6) + lane];
            unsigned u6 = xw[((size_t)(unsigned)i6 << 6) + lane];
            unsigned u7 = xw[((size_t)(unsigned)i7 << 6) + lane];
            a0 += (f32x2){bf_lo(u0), bf_hi(u0)};
            a1 += (f32x2){bf_lo(u1), bf_hi(u1)};
            a2 += (f32x2){bf_lo(u2), bf_hi(u2)};
            a3 += (f32x2){bf_lo(u3), bf_hi(u3)};
            a4 += (f32x2){bf_lo(u4), bf_hi(u4)};
            a5 += (f32x2){bf_lo(u5), bf_hi(u5)};
            a6 += (f32x2){bf_lo(u6), bf_hi(u6)};
            a7 += (f32x2){bf_lo(u7), bf_hi(u7)};
        }
        if (j < d) {
            int nb = d - j;
            // raw loads are safe (within csr allocations); clamp invalid
            // indices to i0 (L1-hit dup row) and zero-weight their adds
            int i0 = csr[s + j + 0];
            int i1r = csr[s + j + 1], i2r = csr[s + j + 2], i3r = csr[s + j + 3];
            int i4r = csr[s + j + 4], i5r = csr[s + j + 5], i6r = csr[s + j + 6];
            int i7r = csr[s + j + 7];
            int i1 = (1 < nb) ? i1r : i0;
            int i2 = (2 < nb) ? i2r : i0;
            int i3 = (3 < nb) ? i3r : i0;
            int i4 = (4 < nb) ? i4r : i0;
            int i5 = (5 < nb) ? i5r : i0;
            int i6 = (6 < nb) ? i6r : i0;
            int i7 = (7 < nb) ? i7r : i0;
            unsigned u0 = xw[((size_t)(unsigned)i0 << 6) + lane];
            unsigned u1 = xw[((size_t)(unsigned)i1 << 6) + lane];
            unsigned u2 = xw[((size_t)(unsigned)i2 << 6) + lane];
            unsigned u3 = xw[((size_t)(unsigned)i3 << 6) + lane];
            unsigned u4 = xw[((size_t)(unsigned)i4 << 6) + lane];
            unsigned u5 = xw[((size_t)(unsigned)i5 << 6) + lane];
            unsigned u6 = xw[((size_t)(unsigned)i6 << 6) + lane];
            unsigned u7 = xw[((size_t)(unsigned)i7 << 6) + lane];
            float w1 = (1 < nb) ? 1.f : 0.f, w2 = (2 < nb) ? 1.f : 0.f;
            float w3 = (3 < nb) ? 1.f : 0.f, w4 = (4 < nb) ? 1.f : 0.f;
            float w5 = (5 < nb) ? 1.f : 0.f, w6 = (6 < nb) ? 1.f : 0.f;
            float w7 = (7 < nb) ? 1.f : 0.f;
            a0 += (f32x2){bf_lo(u0), bf_hi(u0)};
            a1 += (f32x2){bf_lo(u1), bf_hi(u1)} * w1;
            a2 += (f32x2){bf_lo(u2), bf_hi(u2)} * w2;
            a3 += (f32x2){bf_lo(u3), bf_hi(u3)} * w3;
            a4 += (f32x2){bf_lo(u4), bf_hi(u4)} * w4;
            a5 += (f32x2){bf_lo(u5), bf_hi(u5)} * w5;
            a6 += (f32x2){bf_lo(u6), bf_hi(u6)} * w6;
            a7 += (f32x2){bf_lo(u7), bf_hi(u7)} * w7;
        }
        float inv = (d > 0) ? 1.0f / (float)d : 0.f;
        f32x2 r = ((a0 + a1) + (a2 + a3)) + ((a4 + a5) + (a6 + a7));
        unsigned int packed =
            (unsigned int)f2bf(r.x * inv) | ((unsigned int)f2bf(r.y * inv) << 16);
        *(unsigned int*)(aggnb + (long long)node * DIN + lane * 2) = packed;
        if (nvn >= NMID) break;
        nv = nvn;
        node = __builtin_amdgcn_readfirstlane(nvn);
        s = sn; e = en;
    }
}

// out[node] = q[node] + mean_{src in N(node)} p[src]
__global__ __launch_bounds__(256) void gather2_final_kernel(
    const float* __restrict__ p, const float* __restrict__ qb,
    const int* __restrict__ rs, const int* __restrict__ csr,
    float* __restrict__ out)
{
    const int lane = threadIdx.x & 63;
    int nv = blockIdx.x * 4 + (threadIdx.x >> 6);
    if (nv >= NTGT) return;
    int node = __builtin_amdgcn_readfirstlane(nv);
    int s = rs[node];
    int e = rs[node + 1];
    while (true) {
        int nvn = nv + WSTRIDE;
        int sn = 0, en = 0;
        if (nvn < NTGT) {
            int nn = __builtin_amdgcn_readfirstlane(nvn);
            sn = rs[nn];
            en = rs[nn + 1];
        }
        int d = e - s;
        float a0 = 0.f, a1 = 0.f, a2 = 0.f, a3 = 0.f;
        float a4 = 0.f, a5 = 0.f, a6 = 0.f, a7 = 0.f;
        int j = 0;
        for (; j + 8 <= d; j += 8) {
            int i0 = csr[s + j + 0], i1 = csr[s + j + 1];
            int i2 = csr[s + j + 2], i3 = csr[s + j + 3];
            int i4 = csr[s + j + 4], i5 = csr[s + j + 5];
            int i6 = csr[s + j + 6], i7 = csr[s + j + 7];
            a0 += p[((size_t)(unsigned)i0 << 6) + lane];
            a1 += p[((size_t)(unsigned)i1 << 6) + lane];
            a2 += p[((size_t)(unsigned)i2 << 6) + lane];
            a3 += p[((size_t)(unsigned)i3 << 6) + lane];
            a4 += p[((size_t)(unsigned)i4 << 6) + lane];
            a5 += p[((size_t)(unsigned)i5 << 6) + lane];
            a6 += p[((size_t)(unsigned)i6 << 6) + lane];
            a7 += p[((size_t)(unsigned)i7 << 6) + lane];
        }
        if (j < d) {
            int nb = d - j;
            int i0 = csr[s + j + 0];
            int i1r = csr[s + j + 1], i2r = csr[s + j + 2], i3r = csr[s + j + 3];
            int i4r = csr[s + j + 4], i5r = csr[s + j + 5], i6r = csr[s + j + 6];
            int i7r = csr[s + j + 7];
            int i1 = (1 < nb) ? i1r : i0;
            int i2 = (2 < nb) ? i2r : i0;
            int i3 = (3 < nb) ? i3r : i0;
            int i4 = (4 < nb) ? i4r : i0;
            int i5 = (5 < nb) ? i5r : i0;
            int i6 = (6 < nb) ? i6r : i0;
            int i7 = (7 < nb) ? i7r : i0;
            float w1 = (1 < nb) ? 1.f : 0.f, w2 = (2 < nb) ? 1.f : 0.f;
            float w3 = (3 < nb) ? 1.f : 0.f, w4 = (4 < nb) ? 1.f : 0.f;
            float w5 = (5 < nb) ? 1.f : 0.f, w6 = (6 < nb) ? 1.f : 0.f;
            float w7 = (7 < nb) ? 1.f : 0.f;
            a0 += p[((size_t)(unsigned)i0 << 6) + lane];
            a1 += p[((size_t)(unsigned)i1 << 6) + lane] * w1;
            a2 += p[((size_t)(unsigned)i2 << 6) + lane] * w2;
            a3 += p[((size_t)(unsigned)i3 << 6) + lane] * w3;
            a4 += p[((size_t)(unsigned)i4 << 6) + lane] * w4;
            a5 += p[((size_t)(unsigned)i5 << 6) + lane] * w5;
            a6 += p[((size_t)(unsigned)i6 << 6) + lane] * w6;
            a7 += p[((size_t)(unsigned)i7 << 6) + lane] * w7;
        }
        float inv = (d > 0) ? 1.0f / (float)d : 0.f;
        out[(long long)node * DOUT + lane] =
            qb[(long long)node * DOUT + lane] +
            (((a0 + a1) + (a2 + a3)) + ((a4 + a5) + (a6 + a7))) * inv;
        if (nvn >= NTGT) break;
        nv = nvn;
        node = __builtin_amdgcn_readfirstlane(nvn);
        s = sn; e = en;
    }
}

// ---------------- MFMA GEMMs ----------------
#define LDSP 40

// h = relu([aggnb|xb] @ WT1^T + b1), register-prefetch pipelined
__global__ __launch_bounds__(256) void gemm1_mfma(
    const unsigned short* __restrict__ aggnb, const unsigned short* __restrict__ xb,
    const unsigned short* __restrict__ WT, const float* __restrict__ bias,
    unsigned short* __restrict__ h)
{
    __shared__ unsigned short Asm[128 * LDSP];
    __shared__ unsigned short Bsm[128 * LDSP];
    const int tid = threadIdx.x;
    const int bm = blockIdx.x * 128;
    const int bn = blockIdx.y * 128;
    const int wave = tid >> 6, lane = tid & 63;
    const int wr = wave >> 1, wc = wave & 1;
    const int lrow = lane & 15, quad = lane >> 4;

    // per-thread staging coords (2 chunks each for A and B)
    const int c0r = tid >> 2, c0s = tid & 3;          // chunk tid
    const int c1r = (tid + 256) >> 2, c1s = tid & 3;  // chunk tid+256
    int growA0 = bm + c0r; if (growA0 >= NMID) growA0 = NMID - 1;
    int growA1 = bm + c1r; if (growA1 >= NMID) growA1 = NMID - 1;

    uint4 pa0, pa1, pb0, pb1;
    auto gload = [&](int k0) {
        int gk0 = k0 + c0s * 8;
        const unsigned short* sA0 = (gk0 < DIN)
            ? (aggnb + (long long)growA0 * DIN + gk0)
            : (xb + (long long)growA0 * DIN + (gk0 - DIN));
        pa0 = *(const uint4*)sA0;
        const unsigned short* sA1 = (gk0 < DIN)
            ? (aggnb + (long long)growA1 * DIN + gk0)
            : (xb + (long long)growA1 * DIN + (gk0 - DIN));
        pa1 = *(const uint4*)sA1;
        pb0 = *(const uint4*)(WT + (long long)(bn + c0r) * 256 + k0 + c0s * 8);
        pb1 = *(const uint4*)(WT + (long long)(bn + c1r) * 256 + k0 + c1s * 8);
    };

    f32x4 acc[4][4];
    #pragma unroll
    for (int i = 0; i < 4; ++i)
        #pragma unroll
        for (int j = 0; j < 4; ++j)
            acc[i][j] = (f32x4){0.f, 0.f, 0.f, 0.f};

    gload(0);
    for (int it = 0; it < 8; ++it) {
        if (it) __syncthreads();
        *(uint4*)(Asm + c0r * LDSP + c0s * 8) = pa0;
        *(uint4*)(Asm + c1r * LDSP + c1s * 8) = pa1;
        *(uint4*)(Bsm + c0r * LDSP + c0s * 8) = pb0;
        *(uint4*)(Bsm + c1r * LDSP + c1s * 8) = pb1;
        __syncthreads();
        if (it < 7) gload((it + 1) * 32);
        bf16x8 af[4], bfr[4];
        #pragma unroll
        for (int mi = 0; mi < 4; ++mi)
            af[mi] = *(const bf16x8*)(Asm + (wr * 64 + mi * 16 + lrow) * LDSP + quad * 8);
        #pragma unroll
        for (int ni = 0; ni < 4; ++ni)
            bfr[ni] = *(const bf16x8*)(Bsm + (wc * 64 + ni * 16 + lrow) * LDSP + quad * 8);
        #pragma unroll
        for (int mi = 0; mi < 4; ++mi)
            #pragma unroll
            for (int ni = 0; ni < 4; ++ni)
                acc[mi][ni] = __builtin_amdgcn_mfma_f32_16x16x32_bf16(
                    af[mi], bfr[ni], acc[mi][ni], 0, 0, 0);
    }
    #pragma unroll
    for (int mi = 0; mi < 4; ++mi) {
        #pragma unroll
        for (int ni = 0; ni < 4; ++ni) {
            int col = bn + wc * 64 + ni * 16 + lrow;
            float bv = bias[col];
            #pragma unroll
            for (int r = 0; r < 4; ++r) {
                int row = bm + wr * 64 + mi * 16 + quad * 4 + r;
                if (row < NMID) {
                    float v = acc[mi][ni][r] + bv;
                    h[(long long)row * DHID + col] = f2bf(fmaxf(v, 0.0f));
                }
            }
        }
    }
}

// p = h @ Wl2 (all rows); q = h @ Wr2 + b2 (rows < NTGT). WT2: 128 n-rows x 256 k.
__global__ __launch_bounds__(256) void gemm2_dual_mfma(
    const unsigned short* __restrict__ h, const unsigned short* __restrict__ WT2,
    const float* __restrict__ b2,
    float* __restrict__ p, float* __restrict__ qb)
{
    __shared__ unsigned short Asm[128 * LDSP];
    __shared__ unsigned short Bsm[128 * LDSP];
    const int tid = threadIdx.x;
    const int bm = blockIdx.x * 128;
    const int wave = tid >> 6, lane = tid & 63;
    const int lrow = lane & 15, quad = lane >> 4;
    const bool doq = (bm < NTGT);

    const int c0r = tid >> 2, c0s = tid & 3;
    const int c1r = (tid + 256) >> 2;
    int growA0 = bm + c0r; if (growA0 >= NMID) growA0 = NMID - 1;
    int growA1 = bm + c1r; if (growA1 >= NMID) growA1 = NMID - 1;

    uint4 pa0, pa1, pb0, pb1;
    auto gload = [&](int k0) {
        pa0 = *(const uint4*)(h + (long long)growA0 * DHID + k0 + c0s * 8);
        pa1 = *(const uint4*)(h + (long long)growA1 * DHID + k0 + c0s * 8);
        pb0 = *(const uint4*)(WT2 + (long long)c0r * 256 + k0 + c0s * 8);
        pb1 = *(const uint4*)(WT2 + (long long)c1r * 256 + k0 + c0s * 8);
    };

    f32x4 accP[2][4], accQ[2][4];
    #pragma unroll
    for (int i = 0; i < 2; ++i)
        #pragma unroll
        for (int j = 0; j < 4; ++j) {
            accP[i][j] = (f32x4){0.f, 0.f, 0.f, 0.f};
            accQ[i][j] = (f32x4){0.f, 0.f, 0.f, 0.f};
        }

    gload(0);
    for (int it = 0; it < 8; ++it) {
        if (it) __syncthreads();
        *(uint4*)(Asm + c0r * LDSP + c0s * 8) = pa0;
        *(uint4*)(Asm + c1r * LDSP + c0s * 8) = pa1;
        *(uint4*)(Bsm + c0r * LDSP + c0s * 8) = pb0;
        *(uint4*)(Bsm + c1r * LDSP + c0s * 8) = pb1;
        __syncthreads();
        if (it < 7) gload((it + 1) * 32);
        bf16x8 af[2], bp[4];
        #pragma unroll
        for (int mi = 0; mi < 2; ++mi)
            af[mi] = *(const bf16x8*)(Asm + (wave * 32 + mi * 16 + lrow) * LDSP + quad * 8);
        #pragma unroll
        for (int ni = 0; ni < 4; ++ni)
            bp[ni] = *(const bf16x8*)(Bsm + (ni * 16 + lrow) * LDSP + quad * 8);
        #pragma unroll
        for (int mi = 0; mi < 2; ++mi)
            #pragma unroll
            for (int ni = 0; ni < 4; ++ni)
                accP[mi][ni] = __builtin_amdgcn_mfma_f32_16x16x32_bf16(
                    af[mi], bp[ni], accP[mi][ni], 0, 0, 0);
        if (doq) {
            bf16x8 bq[4];
            #pragma unroll
            for (int ni = 0; ni < 4; ++ni)
                bq[ni] = *(const bf16x8*)(Bsm + (64 + ni * 16 + lrow) * LDSP + quad * 8);
            #pragma unroll
            for (int mi = 0; mi < 2; ++mi)
                #pragma unroll
                for (int ni = 0; ni < 4; ++ni)
                    accQ[mi][ni] = __builtin_amdgcn_mfma_f32_16x16x32_bf16(
                        af[mi], bq[ni], accQ[mi][ni], 0, 0, 0);
        }
    }
    #pragma unroll
    for (int mi = 0; mi < 2; ++mi) {
        #pragma unroll
        for (int ni = 0; ni < 4; ++ni) {
            int col = ni * 16 + lrow;
            #pragma unroll
            for (int r = 0; r < 4; ++r) {
                int row = bm + wave * 32 + mi * 16 + quad * 4 + r;
                if (row < NMID)
                    p[(long long)row * DOUT + col] = accP[mi][ni][r];
                if (doq && row < NTGT)
                    qb[(long long)row * DOUT + col] = accQ[mi][ni][r] + b2[col];
            }
        }
    }
}

extern "C" void kernel_launch(void* const* d_in, const int* in_sizes, int n_in,
                              void* d_out, int out_size, void* d_ws, size_t ws_size,
                              hipStream_t stream) {
    const float* x   = (const float*)d_in[0];
    const int*   ei1 = (const int*)d_in[1];
    const int*   ei2 = (const int*)d_in[2];
    const float* Wl1 = (const float*)d_in[3];
    const float* Wr1 = (const float*)d_in[4];
    const float* b1  = (const float*)d_in[5];
    const float* Wl2 = (const float*)d_in[6];
    const float* Wr2 = (const float*)d_in[7];
    const float* b2  = (const float*)d_in[8];
    float* out = (float*)d_out;

    unsigned short* xb    = (unsigned short*)d_ws;
    unsigned short* aggnb = xb + (size_t)NSRC * DIN;
    unsigned short* h     = aggnb + (size_t)NMID * DIN;
    unsigned short* WT1   = h + (size_t)NMID * DHID;
    unsigned short* WT2   = WT1 + 256 * 256;
    float* p    = (float*)(WT2 + 128 * 256);
    float* qb   = p + (size_t)NMID * DOUT;
    int* rs1    = (int*)(qb + (size_t)NTGT * DOUT);
    int* rs2    = rs1 + (NMID + 1);
    int* bhist1 = rs2 + (NTGT + 1);
    int* bhist2 = bhist1 + NBK1;
    int* bbase1 = bhist2 + NBK2;
    int* bbase2 = bbase1 + (NBK1 + 1);
    int* bcur1  = bbase2 + (NBK2 + 1);
    int* bcur2  = bcur1 + NBK1;
    int* csr1   = bcur2 + NBK2 + 1;
    int* csr2   = csr1 + NE1;
    uint2* gbuf1 = (uint2*)(((size_t)(csr2 + NE2) + 15) & ~(size_t)15);
    uint2* gbuf2 = gbuf1 + NE1;

    convert_all_kernel<<<(XCH + 65536 + 32768 + 255) / 256, 256, 0, stream>>>(
        x, Wl1, Wr1, Wl2, Wr2, xb, WT1, WT2);

    hipMemsetAsync(bhist1, 0, (size_t)(NBK1 + NBK2) * 4, stream);
    bucket_hist_kernel<<<NHC1 + NHC2, 256, 0, stream>>>(ei1, ei2, bhist1, bhist2);
    bucket_scan_kernel<<<1, 256, 0, stream>>>(bhist1, bhist2, bbase1, bbase2,
                                              bcur1, bcur2, rs1, rs2);
    bin_kernel<<<NCH1 + NCH2, 256, 0, stream>>>(ei1, ei2, bcur1, bcur2, gbuf1, gbuf2);
    bucket_csr_kernel<<<NBK1 + NBK2, 256, 0, stream>>>(
        gbuf1, gbuf2, bbase1, bbase2, rs1, rs2, csr1, csr2);

    gather1_kernel<<<GBLK, 256, 0, stream>>>(xb, rs1, csr1, aggnb);
    {
        dim3 grid((NMID + 127) / 128, 2);
        gemm1_mfma<<<grid, 256, 0, stream>>>(aggnb, xb, WT1, b1, h);
    }
    gemm2_dual_mfma<<<(NMID + 127) / 128, 256, 0, stream>>>(h, WT2, b2, p, qb);
    gather2_final_kernel<<<GBLK, 256, 0, stream>>>(p, qb, rs2, csr2, out);
}

// Round 7
// 389.297 us; speedup vs baseline: 1.0427x; 1.0427x over previous
//
#include <hip/hip_runtime.h>

// GraphSAGE 2-layer. Round 14 (= round 11 kernel, fourth submit; rounds
// 11/12/13 all hit GPUAcquisitionTimeout before execution): gathers in
// round-8 form (best measured; r9 MLP-boost regressed — gather1 is at its
// L2-miss-path wall). New vs r8: p stored as bf16 (halves gather2 stream,
// 12.8MB L2-resident); convert_all merged into bucket_hist launch
// (independent DAG roots overlap).

#define NSRC 200000
#define NMID 100000
#define NTGT 50000
#define NE1  1600000
#define NE2  800000
#define DIN  128
#define DHID 256
#define DOUT 64

#define XCH (NSRC * 16)

#define CH   4096
#define NBK1 391
#define NBK2 196
#define NCH1 ((NE1 + CH - 1) / CH)
#define NCH2 ((NE2 + CH - 1) / CH)
#define HCH  8192
#define NHC1 ((NE1 + HCH - 1) / HCH)
#define NHC2 ((NE2 + HCH - 1) / HCH)
#define NHIST (NHC1 + NHC2)
#define CVB ((XCH + 65536 + 32768 + 255) / 256)
#define MAXBUF 6144

typedef __attribute__((ext_vector_type(8))) short bf16x8;
typedef __attribute__((ext_vector_type(4))) float f32x4;
typedef __attribute__((ext_vector_type(2))) float f32x2;

__device__ __forceinline__ unsigned short f2bf(float f) {
    unsigned int u = __builtin_bit_cast(unsigned int, f);
    u += 0x7FFFu + ((u >> 16) & 1u);
    return (unsigned short)(u >> 16);
}
__device__ __forceinline__ float bf_lo(unsigned int u) {
    return __builtin_bit_cast(float, u << 16);
}
__device__ __forceinline__ float bf_hi(unsigned int u) {
    return __builtin_bit_cast(float, u & 0xFFFF0000u);
}
__device__ __forceinline__ float bf1(unsigned short u) {
    return __builtin_bit_cast(float, (unsigned int)u << 16);
}

// ---------------- fused convert + bucket hist (independent DAG roots) ------
__global__ __launch_bounds__(256) void conv_hist_kernel(
    const float* __restrict__ x,
    const float* __restrict__ Wl1, const float* __restrict__ Wr1,
    const float* __restrict__ Wl2, const float* __restrict__ Wr2,
    unsigned short* __restrict__ xb, unsigned short* __restrict__ WT1,
    unsigned short* __restrict__ WT2,
    const int* __restrict__ ei1, const int* __restrict__ ei2,
    int* __restrict__ bhist1, int* __restrict__ bhist2)
{
    __shared__ unsigned int lh[512];
    if (blockIdx.x < NHIST) {
        // ---- bucket histogram branch ----
        const int* ei; int* bh; int nE, nbk, chunk;
        if (blockIdx.x < NHC1) { ei = ei1; bh = bhist1; nE = NE1; nbk = NBK1; chunk = blockIdx.x; }
        else { ei = ei2; bh = bhist2; nE = NE2; nbk = NBK2; chunk = blockIdx.x - NHC1; }
        int t = threadIdx.x;
        lh[t] = 0; lh[t + 256] = 0;
        __syncthreads();
        int base = chunk * HCH;
        int end = nE < base + HCH ? nE : base + HCH;
        for (int e = base + t; e < end; e += 256)
            atomicAdd(&lh[((unsigned)ei[nE + e]) >> 8], 1u);
        __syncthreads();
        if (t < nbk && lh[t]) atomicAdd(&bh[t], (int)lh[t]);
        if (t + 256 < nbk && lh[t + 256]) atomicAdd(&bh[t + 256], (int)lh[t + 256]);
        return;
    }
    // ---- convert branch ----
    int gid = (blockIdx.x - NHIST) * 256 + threadIdx.x;
    if (gid < XCH) {
        const float4 v0 = *(const float4*)(x + (long long)gid * 8);
        const float4 v1 = *(const float4*)(x + (long long)gid * 8 + 4);
        unsigned short o[8] = {f2bf(v0.x), f2bf(v0.y), f2bf(v0.z), f2bf(v0.w),
                               f2bf(v1.x), f2bf(v1.y), f2bf(v1.z), f2bf(v1.w)};
        *(uint4*)(xb + (long long)gid * 8) = *(const uint4*)o;
        return;
    }
    int g = gid - XCH;
    if (g < 65536) {
        int n = g >> 8, k = g & 255;
        float v = (k < DIN) ? Wl1[(long long)k * DHID + n]
                            : Wr1[(long long)(k - DIN) * DHID + n];
        WT1[g] = f2bf(v);
        return;
    }
    g -= 65536;
    if (g < 32768) {
        int n2 = g >> 8, k = g & 255;
        float v = (n2 < DOUT) ? Wl2[(long long)k * DOUT + n2]
                              : Wr2[(long long)k * DOUT + (n2 - DOUT)];
        WT2[g] = f2bf(v);
    }
}

// ---------------- bucket-first CSR build ----------------

__global__ __launch_bounds__(256) void bucket_scan_kernel(
    const int* __restrict__ bhist1, const int* __restrict__ bhist2,
    int* __restrict__ bbase1, int* __restrict__ bbase2,
    int* __restrict__ bcur1, int* __restrict__ bcur2,
    int* __restrict__ rs1, int* __restrict__ rs2)
{
    __shared__ int s[256];
    int t = threadIdx.x;
    int a0 = (2 * t < NBK1) ? bhist1[2 * t] : 0;
    int a1 = (2 * t + 1 < NBK1) ? bhist1[2 * t + 1] : 0;
    s[t] = a0 + a1;
    __syncthreads();
    for (int off = 1; off < 256; off <<= 1) {
        int u = (t >= off) ? s[t - off] : 0;
        __syncthreads();
        s[t] += u;
        __syncthreads();
    }
    int ex = (t > 0) ? s[t - 1] : 0;
    if (2 * t < NBK1)     { bbase1[2 * t] = ex;      bcur1[2 * t] = ex; }
    if (2 * t + 1 < NBK1) { bbase1[2 * t + 1] = ex + a0; bcur1[2 * t + 1] = ex + a0; }
    if (t == 0) { bbase1[NBK1] = NE1; rs1[NMID] = NE1; bbase2[NBK2] = NE2; rs2[NTGT] = NE2; }
    __syncthreads();
    int b0 = (t < NBK2) ? bhist2[t] : 0;
    s[t] = b0;
    __syncthreads();
    for (int off = 1; off < 256; off <<= 1) {
        int u = (t >= off) ? s[t - off] : 0;
        __syncthreads();
        s[t] += u;
        __syncthreads();
    }
    int ex2 = (t > 0) ? s[t - 1] : 0;
    if (t < NBK2) { bbase2[t] = ex2; bcur2[t] = ex2; }
}

__global__ __launch_bounds__(256) void bin_kernel(
    const int* __restrict__ ei1, const int* __restrict__ ei2,
    int* __restrict__ bcur1, int* __restrict__ bcur2,
    uint2* __restrict__ gbuf1, uint2* __restrict__ gbuf2)
{
    __shared__ unsigned int lcnt[512];
    __shared__ unsigned int lofs[512];
    __shared__ unsigned int lpos[512];
    __shared__ unsigned int gbase[512];
    __shared__ unsigned int swarp[256];
    __shared__ uint2 lbuf[CH];

    const int* ei; int* bcur; uint2* gbuf; int nE, nbk, chunk;
    if (blockIdx.x < NCH1) {
        ei = ei1; bcur = bcur1; gbuf = gbuf1; nE = NE1; nbk = NBK1; chunk = blockIdx.x;
    } else {
        ei = ei2; bcur = bcur2; gbuf = gbuf2; nE = NE2; nbk = NBK2; chunk = blockIdx.x - NCH1;
    }
    int base = chunk * CH;
    int nb = nE - base; if (nb > CH) nb = CH;
    int t = threadIdx.x;

    for (int i = t; i < 512; i += 256) { lcnt[i] = 0; lpos[i] = 0; }
    __syncthreads();

    int srcv[16], tgtv[16];
    #pragma unroll
    for (int i = 0; i < 16; ++i) {
        int e = base + i * 256 + t;
        if (e < nE) {
            tgtv[i] = ei[nE + e];
            srcv[i] = ei[e];
            atomicAdd(&lcnt[tgtv[i] >> 8], 1u);
        } else tgtv[i] = -1;
    }
    __syncthreads();

    unsigned a0 = lcnt[2 * t], a1 = lcnt[2 * t + 1];
    swarp[t] = a0 + a1;
    __syncthreads();
    for (int off = 1; off < 256; off <<= 1) {
        unsigned v = (t >= off) ? swarp[t - off] : 0;
        __syncthreads();
        swarp[t] += v;
        __syncthreads();
    }
    unsigned ex = (t > 0) ? swarp[t - 1] : 0;
    lofs[2 * t] = ex;
    lofs[2 * t + 1] = ex + a0;
    if (2 * t < nbk && a0) gbase[2 * t] = atomicAdd(&bcur[2 * t], (int)a0);
    if (2 * t + 1 < nbk && a1) gbase[2 * t + 1] = atomicAdd(&bcur[2 * t + 1], (int)a1);
    __syncthreads();

    #pragma unroll
    for (int i = 0; i < 16; ++i) {
        if (tgtv[i] >= 0) {
            int b = tgtv[i] >> 8;
            unsigned idx = lofs[b] + atomicAdd(&lpos[b], 1u);
            lbuf[idx] = make_uint2((unsigned)srcv[i], (unsigned)tgtv[i]);
        }
    }
    __syncthreads();

    for (int i = t; i < nb; i += 256) {
        uint2 r = lbuf[i];
        int b = (int)(r.y >> 8);
        unsigned gi = gbase[b] + ((unsigned)i - lofs[b]);
        gbuf[gi] = r;
    }
}

__global__ __launch_bounds__(256) void bucket_csr_kernel(
    const uint2* __restrict__ gbuf1, const uint2* __restrict__ gbuf2,
    const int* __restrict__ bbase1, const int* __restrict__ bbase2,
    int* __restrict__ rs1, int* __restrict__ rs2,
    int* __restrict__ csr1, int* __restrict__ csr2)
{
    __shared__ unsigned int lhist[256];
    __shared__ unsigned int lcur[256];
    __shared__ unsigned int sscan[256];
    __shared__ unsigned int lbuf[MAXBUF];
    const uint2* gbuf; const int* bbase; int* rs; int* csr; int bucket, ntot;
    if (blockIdx.x < NBK1) {
        gbuf = gbuf1; bbase = bbase1; rs = rs1; csr = csr1; bucket = blockIdx.x; ntot = NMID;
    } else {
        gbuf = gbuf2; bbase = bbase2; rs = rs2; csr = csr2; bucket = blockIdx.x - NBK1; ntot = NTGT;
    }
    int base = bbase[bucket];
    int size = bbase[bucket + 1] - base;
    int node0 = bucket << 8;
    int nnode = ntot - node0; if (nnode > 256) nnode = 256;
    int t = threadIdx.x;
    lhist[t] = 0;
    __syncthreads();
    for (int i = t; i < size; i += 256)
        atomicAdd(&lhist[gbuf[base + i].y & 255], 1u);
    __syncthreads();
    unsigned v = lhist[t];
    sscan[t] = v;
    __syncthreads();
    for (int off = 1; off < 256; off <<= 1) {
        unsigned u = (t >= off) ? sscan[t - off] : 0;
        __syncthreads();
        sscan[t] += u;
        __syncthreads();
    }
    unsigned ex = (t > 0) ? sscan[t - 1] : 0;
    lcur[t] = ex;
    if (t < nnode) rs[node0 + t] = base + (int)ex;
    __syncthreads();
    for (int i = t; i < size; i += 256) {
        uint2 r = gbuf[base + i];
        unsigned pos = atomicAdd(&lcur[r.y & 255], 1u);
        lbuf[pos] = r.x;
    }
    __syncthreads();
    for (int i = t; i < size; i += 256)
        csr[base + i] = (int)lbuf[i];
}

// ---------------- gathers (round-8 form: scalarized, 4-wide) ----------------
// One wave per node. node forced into SGPR so rs/csr reads are s_load and row
// loads use the saddr form (zero per-edge VALU address math).

__global__ __launch_bounds__(256) void gather1_kernel(
    const unsigned short* __restrict__ xb, const int* __restrict__ rs,
    const int* __restrict__ csr, unsigned short* __restrict__ aggnb)
{
    int wid = threadIdx.x >> 6;
    int lane = threadIdx.x & 63;
    int node = __builtin_amdgcn_readfirstlane(blockIdx.x * 4 + wid);
    if (node >= NMID) return;
    int s = rs[node];
    int d = rs[node + 1] - s;
    const unsigned int* xw = (const unsigned int*)xb;   // 64 uints per row
    f32x2 a0 = {0.f, 0.f}, a1 = {0.f, 0.f}, a2 = {0.f, 0.f}, a3 = {0.f, 0.f};
    int j = 0;
    for (; j + 3 < d; j += 4) {
        int i0 = csr[s + j];
        int i1 = csr[s + j + 1];
        int i2 = csr[s + j + 2];
        int i3 = csr[s + j + 3];
        unsigned int u0 = xw[((size_t)(unsigned)i0 << 6) + lane];
        unsigned int u1 = xw[((size_t)(unsigned)i1 << 6) + lane];
        unsigned int u2 = xw[((size_t)(unsigned)i2 << 6) + lane];
        unsigned int u3 = xw[((size_t)(unsigned)i3 << 6) + lane];
        a0 += (f32x2){bf_lo(u0), bf_hi(u0)};
        a1 += (f32x2){bf_lo(u1), bf_hi(u1)};
        a2 += (f32x2){bf_lo(u2), bf_hi(u2)};
        a3 += (f32x2){bf_lo(u3), bf_hi(u3)};
    }
    for (; j < d; ++j) {
        int i0 = csr[s + j];
        unsigned int u0 = xw[((size_t)(unsigned)i0 << 6) + lane];
        a0 += (f32x2){bf_lo(u0), bf_hi(u0)};
    }
    float inv = (d > 0) ? 1.0f / (float)d : 0.f;
    f32x2 r = (a0 + a1) + (a2 + a3);
    float r0 = r.x * inv;
    float r1 = r.y * inv;
    unsigned int packed = (unsigned int)f2bf(r0) | ((unsigned int)f2bf(r1) << 16);
    *(unsigned int*)(aggnb + (long long)node * DIN + lane * 2) = packed;
}

// out[node] = q[node] + mean_{src in N(node)} p[src]; p is bf16 (64/row)
__global__ __launch_bounds__(256) void gather2_final_kernel(
    const unsigned short* __restrict__ pb, const float* __restrict__ qb,
    const int* __restrict__ rs, const int* __restrict__ csr,
    float* __restrict__ out)
{
    int wid = threadIdx.x >> 6;
    int lane = threadIdx.x & 63;
    int node = __builtin_amdgcn_readfirstlane(blockIdx.x * 4 + wid);
    if (node >= NTGT) return;
    int s = rs[node];
    int d = rs[node + 1] - s;
    float a0 = 0.f, a1 = 0.f, a2 = 0.f, a3 = 0.f;
    int j = 0;
    for (; j + 3 < d; j += 4) {
        int i0 = csr[s + j];
        int i1 = csr[s + j + 1];
        int i2 = csr[s + j + 2];
        int i3 = csr[s + j + 3];
        a0 += bf1(pb[((size_t)(unsigned)i0 << 6) + lane]);
        a1 += bf1(pb[((size_t)(unsigned)i1 << 6) + lane]);
        a2 += bf1(pb[((size_t)(unsigned)i2 << 6) + lane]);
        a3 += bf1(pb[((size_t)(unsigned)i3 << 6) + lane]);
    }
    for (; j < d; ++j) {
        int i0 = csr[s + j];
        a0 += bf1(pb[((size_t)(unsigned)i0 << 6) + lane]);
    }
    float inv = (d > 0) ? 1.0f / (float)d : 0.f;
    out[(long long)node * DOUT + lane] =
        qb[(long long)node * DOUT + lane] + ((a0 + a1) + (a2 + a3)) * inv;
}

// ---------------- MFMA GEMMs ----------------
#define LDSP 40

// h = relu([aggnb|xb] @ WT1^T + b1), register-prefetch pipelined
__global__ __launch_bounds__(256) void gemm1_mfma(
    const unsigned short* __restrict__ aggnb, const unsigned short* __restrict__ xb,
    const unsigned short* __restrict__ WT, const float* __restrict__ bias,
    unsigned short* __restrict__ h)
{
    __shared__ unsigned short Asm[128 * LDSP];
    __shared__ unsigned short Bsm[128 * LDSP];
    const int tid = threadIdx.x;
    const int bm = blockIdx.x * 128;
    const int bn = blockIdx.y * 128;
    const int wave = tid >> 6, lane = tid & 63;
    const int wr = wave >> 1, wc = wave & 1;
    const int lrow = lane & 15, quad = lane >> 4;

    // per-thread staging coords (2 chunks each for A and B)
    const int c0r = tid >> 2, c0s = tid & 3;          // chunk tid
    const int c1r = (tid + 256) >> 2, c1s = tid & 3;  // chunk tid+256
    int growA0 = bm + c0r; if (growA0 >= NMID) growA0 = NMID - 1;
    int growA1 = bm + c1r; if (growA1 >= NMID) growA1 = NMID - 1;

    uint4 pa0, pa1, pb0, pb1;
    auto gload = [&](int k0) {
        int gk0 = k0 + c0s * 8;
        const unsigned short* sA0 = (gk0 < DIN)
            ? (aggnb + (long long)growA0 * DIN + gk0)
            : (xb + (long long)growA0 * DIN + (gk0 - DIN));
        pa0 = *(const uint4*)sA0;
        const unsigned short* sA1 = (gk0 < DIN)
            ? (aggnb + (long long)growA1 * DIN + gk0)
            : (xb + (long long)growA1 * DIN + (gk0 - DIN));
        pa1 = *(const uint4*)sA1;
        pb0 = *(const uint4*)(WT + (long long)(bn + c0r) * 256 + k0 + c0s * 8);
        pb1 = *(const uint4*)(WT + (long long)(bn + c1r) * 256 + k0 + c1s * 8);
    };

    f32x4 acc[4][4];
    #pragma unroll
    for (int i = 0; i < 4; ++i)
        #pragma unroll
        for (int j = 0; j < 4; ++j)
            acc[i][j] = (f32x4){0.f, 0.f, 0.f, 0.f};

    gload(0);
    for (int it = 0; it < 8; ++it) {
        if (it) __syncthreads();
        *(uint4*)(Asm + c0r * LDSP + c0s * 8) = pa0;
        *(uint4*)(Asm + c1r * LDSP + c1s * 8) = pa1;
        *(uint4*)(Bsm + c0r * LDSP + c0s * 8) = pb0;
        *(uint4*)(Bsm + c1r * LDSP + c1s * 8) = pb1;
        __syncthreads();
        if (it < 7) gload((it + 1) * 32);
        bf16x8 af[4], bfr[4];
        #pragma unroll
        for (int mi = 0; mi < 4; ++mi)
            af[mi] = *(const bf16x8*)(Asm + (wr * 64 + mi * 16 + lrow) * LDSP + quad * 8);
        #pragma unroll
        for (int ni = 0; ni < 4; ++ni)
            bfr[ni] = *(const bf16x8*)(Bsm + (wc * 64 + ni * 16 + lrow) * LDSP + quad * 8);
        #pragma unroll
        for (int mi = 0; mi < 4; ++mi)
            #pragma unroll
            for (int ni = 0; ni < 4; ++ni)
                acc[mi][ni] = __builtin_amdgcn_mfma_f32_16x16x32_bf16(
                    af[mi], bfr[ni], acc[mi][ni], 0, 0, 0);
    }
    #pragma unroll
    for (int mi = 0; mi < 4; ++mi) {
        #pragma unroll
        for (int ni = 0; ni < 4; ++ni) {
            int col = bn + wc * 64 + ni * 16 + lrow;
            float bv = bias[col];
            #pragma unroll
            for (int r = 0; r < 4; ++r) {
                int row = bm + wr * 64 + mi * 16 + quad * 4 + r;
                if (row < NMID) {
                    float v = acc[mi][ni][r] + bv;
                    h[(long long)row * DHID + col] = f2bf(fmaxf(v, 0.0f));
                }
            }
        }
    }
}

// p = h @ Wl2 (all rows, bf16 out); q = h @ Wr2 + b2 (rows < NTGT, f32 out).
// WT2: 128 n-rows x 256 k.
__global__ __launch_bounds__(256) void gemm2_dual_mfma(
    const unsigned short* __restrict__ h, const unsigned short* __restrict__ WT2,
    const float* __restrict__ b2,
    unsigned short* __restrict__ pb, float* __restrict__ qb)
{
    __shared__ unsigned short Asm[128 * LDSP];
    __shared__ unsigned short Bsm[128 * LDSP];
    const int tid = threadIdx.x;
    const int bm = blockIdx.x * 128;
    const int wave = tid >> 6, lane = tid & 63;
    const int lrow = lane & 15, quad = lane >> 4;
    const bool doq = (bm < NTGT);

    const int c0r = tid >> 2, c0s = tid & 3;
    const int c1r = (tid + 256) >> 2;
    int growA0 = bm + c0r; if (growA0 >= NMID) growA0 = NMID - 1;
    int growA1 = bm + c1r; if (growA1 >= NMID) growA1 = NMID - 1;

    uint4 pa0, pa1, pb0, pb1;
    auto gload = [&](int k0) {
        pa0 = *(const uint4*)(h + (long long)growA0 * DHID + k0 + c0s * 8);
        pa1 = *(const uint4*)(h + (long long)growA1 * DHID + k0 + c0s * 8);
        pb0 = *(const uint4*)(WT2 + (long long)c0r * 256 + k0 + c0s * 8);
        pb1 = *(const uint4*)(WT2 + (long long)c1r * 256 + k0 + c0s * 8);
    };

    f32x4 accP[2][4], accQ[2][4];
    #pragma unroll
    for (int i = 0; i < 2; ++i)
        #pragma unroll
        for (int j = 0; j < 4; ++j) {
            accP[i][j] = (f32x4){0.f, 0.f, 0.f, 0.f};
            accQ[i][j] = (f32x4){0.f, 0.f, 0.f, 0.f};
        }

    gload(0);
    for (int it = 0; it < 8; ++it) {
        if (it) __syncthreads();
        *(uint4*)(Asm + c0r * LDSP + c0s * 8) = pa0;
        *(uint4*)(Asm + c1r * LDSP + c0s * 8) = pa1;
        *(uint4*)(Bsm + c0r * LDSP + c0s * 8) = pb0;
        *(uint4*)(Bsm + c1r * LDSP + c0s * 8) = pb1;
        __syncthreads();
        if (it < 7) gload((it + 1) * 32);
        bf16x8 af[2], bp[4];
        #pragma unroll
        for (int mi = 0; mi < 2; ++mi)
            af[mi] = *(const bf16x8*)(Asm + (wave * 32 + mi * 16 + lrow) * LDSP + quad * 8);
        #pragma unroll
        for (int ni = 0; ni < 4; ++ni)
            bp[ni] = *(const bf16x8*)(Bsm + (ni * 16 + lrow) * LDSP + quad * 8);
        #pragma unroll
        for (int mi = 0; mi < 2; ++mi)
            #pragma unroll
            for (int ni = 0; ni < 4; ++ni)
                accP[mi][ni] = __builtin_amdgcn_mfma_f32_16x16x32_bf16(
                    af[mi], bp[ni], accP[mi][ni], 0, 0, 0);
        if (doq) {
            bf16x8 bq[4];
            #pragma unroll
            for (int ni = 0; ni < 4; ++ni)
                bq[ni] = *(const bf16x8*)(Bsm + (64 + ni * 16 + lrow) * LDSP + quad * 8);
            #pragma unroll
            for (int mi = 0; mi < 2; ++mi)
                #pragma unroll
                for (int ni = 0; ni < 4; ++ni)
                    accQ[mi][ni] = __builtin_amdgcn_mfma_f32_16x16x32_bf16(
                        af[mi], bq[ni], accQ[mi][ni], 0, 0, 0);
        }
    }
    #pragma unroll
    for (int mi = 0; mi < 2; ++mi) {
        #pragma unroll
        for (int ni = 0; ni < 4; ++ni) {
            int col = ni * 16 + lrow;
            #pragma unroll
            for (int r = 0; r < 4; ++r) {
                int row = bm + wave * 32 + mi * 16 + quad * 4 + r;
                if (row < NMID)
                    pb[(long long)row * DOUT + col] = f2bf(accP[mi][ni][r]);
                if (doq && row < NTGT)
                    qb[(long long)row * DOUT + col] = accQ[mi][ni][r] + b2[col];
            }
        }
    }
}

extern "C" void kernel_launch(void* const* d_in, const int* in_sizes, int n_in,
                              void* d_out, int out_size, void* d_ws, size_t ws_size,
                              hipStream_t stream) {
    const float* x   = (const float*)d_in[0];
    const int*   ei1 = (const int*)d_in[1];
    const int*   ei2 = (const int*)d_in[2];
    const float* Wl1 = (const float*)d_in[3];
    const float* Wr1 = (const float*)d_in[4];
    const float* b1  = (const float*)d_in[5];
    const float* Wl2 = (const float*)d_in[6];
    const float* Wr2 = (const float*)d_in[7];
    const float* b2  = (const float*)d_in[8];
    float* out = (float*)d_out;

    unsigned short* xb    = (unsigned short*)d_ws;
    unsigned short* aggnb = xb + (size_t)NSRC * DIN;
    unsigned short* h     = aggnb + (size_t)NMID * DIN;
    unsigned short* WT1   = h + (size_t)NMID * DHID;
    unsigned short* WT2   = WT1 + 256 * 256;
    unsigned short* pb    = WT2 + 128 * 256;              // bf16 p: NMID x 64
    float* qb   = (float*)(pb + (size_t)NMID * DOUT);
    int* rs1    = (int*)(qb + (size_t)NTGT * DOUT);
    int* rs2    = rs1 + (NMID + 1);
    int* bhist1 = rs2 + (NTGT + 1);
    int* bhist2 = bhist1 + NBK1;
    int* bbase1 = bhist2 + NBK2;
    int* bbase2 = bbase1 + (NBK1 + 1);
    int* bcur1  = bbase2 + (NBK2 + 1);
    int* bcur2  = bcur1 + NBK1;
    int* csr1   = bcur2 + NBK2 + 1;
    int* csr2   = csr1 + NE1;
    uint2* gbuf1 = (uint2*)(((size_t)(csr2 + NE2) + 15) & ~(size_t)15);
    uint2* gbuf2 = gbuf1 + NE1;

    hipMemsetAsync(bhist1, 0, (size_t)(NBK1 + NBK2) * 4, stream);
    conv_hist_kernel<<<NHIST + CVB, 256, 0, stream>>>(
        x, Wl1, Wr1, Wl2, Wr2, xb, WT1, WT2, ei1, ei2, bhist1, bhist2);
    bucket_scan_kernel<<<1, 256, 0, stream>>>(bhist1, bhist2, bbase1, bbase2,
                                              bcur1, bcur2, rs1, rs2);
    bin_kernel<<<NCH1 + NCH2, 256, 0, stream>>>(ei1, ei2, bcur1, bcur2, gbuf1, gbuf2);
    bucket_csr_kernel<<<NBK1 + NBK2, 256, 0, stream>>>(
        gbuf1, gbuf2, bbase1, bbase2, rs1, rs2, csr1, csr2);

    gather1_kernel<<<(NMID + 3) / 4, 256, 0, stream>>>(xb, rs1, csr1, aggnb);
    {
        dim3 grid((NMID + 127) / 128, 2);
        gemm1_mfma<<<grid, 256, 0, stream>>>(aggnb, xb, WT1, b1, h);
    }
    gemm2_dual_mfma<<<(NMID + 127) / 128, 256, 0, stream>>>(h, WT2, b2, pb, qb);
    gather2_final_kernel<<<(NTGT + 3) / 4, 256, 0, stream>>>(pb, qb, rs2, csr2, out);
}